// Round 13
// baseline (149.034 us; speedup 1.0000x reference)
//
#include <hip/hip_runtime.h>
#include <hip/hip_bf16.h>
#include <hip/hip_cooperative_groups.h>
namespace cg = cooperative_groups;

// Problem constants: B=32, T=256, N=1024 -> R = 8192 rows, K = N-1 = 1023 (padded to 1024)
// alpha = 0.5, b[m] = sqrt(m+1)-sqrt(m) = 1/(sqrt(m+1)+sqrt(m)), coef = sqrt(1023)/Gamma(1.5)
#define COEF 36.090511f
#define INV_COUNT (1.0f / 8388608.0f)   // 1 / (32*256*1024)

typedef __attribute__((ext_vector_type(4))) float f32x4;
typedef __attribute__((ext_vector_type(2))) unsigned long long u64x2;

typedef const __attribute__((address_space(1))) unsigned int* gas_ptr;
typedef __attribute__((address_space(3))) unsigned int* las_ptr;

__device__ __forceinline__ void load_lds16(const void* g, void* l) {
  __builtin_amdgcn_global_load_lds((gas_ptr)g, (las_ptr)l, 16, 0, 0);
}

// manual OCP e4m3fn decode (bias 7): exact
__device__ __forceinline__ float fp8_dec(unsigned int v) {
  const unsigned e = (v >> 3) & 0xF, m = v & 7;
  const int mant = e ? (8 + (int)m) : (int)m;
  const int ee = e ? (int)e : 1;
  float f = (float)mant * __int_as_float((ee + 117) << 23);  // mant * 2^(ee-10)
  return (v & 0x80) ? -f : f;
}

// ---- phase 1 body: prep (512 blocks x 512 threads) ----
// Each block preps 16 du rows (32 threads/row, interleaved 4-col chunks, coalesced) with
// XCD-local mapping: block bid (lands on XCD bid&7) writes rows [((bid&7)*64+(bid>>3))*16, +16)
// = exactly the A-panel its XCD's gemm blocks read -> du8 slice stays in local L2.
// Also fills Mt8 (4 bytes/thread) and dpart/ppart.
__device__ __forceinline__ void prep_body(
    int bid, int t,
    const float* __restrict__ up, const float* __restrict__ utr,
    unsigned char* __restrict__ du8, unsigned char* __restrict__ Mt8,
    float* __restrict__ dpart, float* __restrict__ ppart) {
  const int r = (((bid & 7) * 64 + (bid >> 3)) << 4) + (t >> 5);
  const int tg = t & 31;
  const float* rowp = up + (size_t)r * 1024;
  const float* rowq = utr + (size_t)r * 1024;

  f32x4 a[8];
#pragma unroll
  for (int i = 0; i < 8; i++) a[i] = *(const f32x4*)(rowp + i * 128 + tg * 4);

  float dsum = 0.f;
#pragma unroll
  for (int i = 0; i < 8; i++) {
    // u[chunk_end]: lane tg reads lane (tg+1)&31; lane 0 supplies next i-chunk's first elem
    float supply = (tg == 0) ? ((i < 7) ? a[i + 1][0] : 0.f) : a[i][0];
    float nxt = __shfl(supply, (tg + 1) & 31, 32);
    float d0 = a[i][1] - a[i][0];
    float d1 = a[i][2] - a[i][1];
    float d2 = a[i][3] - a[i][2];
    float d3 = nxt - a[i][3];
    if (i == 7 && tg == 31) d3 = 0.f;            // du[1023] = 0 pad
    int w_ = __builtin_amdgcn_cvt_pk_fp8_f32(d0, d1, 0, false);
    w_ = __builtin_amdgcn_cvt_pk_fp8_f32(d2, d3, w_, true);
    *(unsigned int*)(du8 + (size_t)r * 1024 + i * 128 + tg * 4) = (unsigned int)w_;
    if (i == 0 && tg == 0) ppart[r] = d0 * d0;   // n=0 residual: u_t = du[r,0]
    f32x4 b4 = *(const f32x4*)(rowq + i * 128 + tg * 4);
    float e0 = a[i][0] - b4[0], e1 = a[i][1] - b4[1];
    float e2 = a[i][2] - b4[2], e3 = a[i][3] - b4[3];
    dsum += e0 * e0 + e1 * e1 + e2 * e2 + e3 * e3;
  }
#pragma unroll
  for (int off = 16; off > 0; off >>= 1) dsum += __shfl_down(dsum, off, 32);
  if (tg == 0) dpart[r] = dsum;

  // Mt8[i][j] = fp8(b[i-j]) — 4 bytes per thread
  const int g = bid * 512 + t;
  const int mi = g >> 8;
  const int mj0 = (g & 255) * 4;
  float v[4];
#pragma unroll
  for (int e2 = 0; e2 < 4; e2++) {
    int m = mi - (mj0 + e2);
    v[e2] = 0.f;
    if (m >= 0) { float fm_ = (float)m; v[e2] = 1.0f / (sqrtf(fm_ + 1.f) + sqrtf(fm_)); }
  }
  int w_ = __builtin_amdgcn_cvt_pk_fp8_f32(v[0], v[1], 0, false);
  w_ = __builtin_amdgcn_cvt_pk_fp8_f32(v[2], v[3], w_, true);
  *(unsigned int*)(Mt8 + (size_t)mi * 1024 + mj0) = (unsigned int)w_;
}

// ---- phase 2 body: fp8 GEMM + fused epilogue (identical structure to R12) ----
__device__ __forceinline__ void gemm_body(
    int bid, int t,
    const unsigned char* __restrict__ du8, const unsigned char* __restrict__ Mt8,
    float* __restrict__ gpart,
    const float* __restrict__ dpart, const float* __restrict__ ppart) {
  __shared__ unsigned char sA[2][16384];   // [128 rows][128 k-bytes], quad-swizzled
  __shared__ unsigned char sB[2][16384];
  __shared__ float wsum[8];

  const int w = t >> 6;
  const int lane = t & 63;

  const int xcd = bid & 7;
  const int local = bid >> 3;      // 0..63
  const int e = local & 1;
  const int j = local >> 1;        // 0..31
  const int h = (j < 16) ? (j & 7) : 7 - (j & 7);
  const int cb = e ? 7 - h : h;                 // pairs (2k,2k+1) and (k,k+32) both sum to 7
  const int rb = xcd * 8 + (((j >> 3) << 1) | e);   // bijective with cb per XCD
  const int row0 = rb * 128;
  const int col0 = cb * 128;
  const int nkb = cb + 1;          // K-blocks of 128 bytes (triangular skip)

  const f32x4 vzero = {0.f, 0.f, 0.f, 0.f};
  f32x4 acc[4][2];
#pragma unroll
  for (int i = 0; i < 4; i++)
#pragma unroll
    for (int jj = 0; jj < 2; jj++) acc[i][jj] = vzero;

  // staging: 512 threads x 16B = 8KB/call -> 2 calls per 16KB tile.
  const int srow = t >> 3;                            // 0..63
  const int scol = ((t & 7) ^ (srow & 7)) * 16;       // pre-swizzled source byte col
  const unsigned char* gA0 = du8 + (size_t)(row0 + srow) * 1024 + scol;
  const unsigned char* gB0 = Mt8 + (size_t)(col0 + srow) * 1024 + scol;

  auto stage = [&](int buf, int kb) {
    const int kc = kb * 128;
#pragma unroll
    for (int l = 0; l < 2; l++)
      load_lds16(gA0 + (size_t)l * 64 * 1024 + kc, (void*)&sA[buf][l * 8192 + t * 16]);
#pragma unroll
    for (int l = 0; l < 2; l++)
      load_lds16(gB0 + (size_t)l * 64 * 1024 + kc, (void*)&sB[buf][l * 8192 + t * 16]);
  };

  const int wm = w >> 2, wn = w & 3;     // wave quadrant: rows wm*64, cols wn*32
  const int frow = lane & 15;
  const int g4 = lane >> 4;              // lane's k-owner group 0..3

  auto compute = [&](int buf) {
#pragma unroll
    for (int p = 0; p < 2; p++) {
      const int lq = g4 * 2 + p;               // logical quad
      const int ph = lq ^ (frow & 7);          // physical quad (swizzle)
      u64x2 aV[4], bV[2];
#pragma unroll
      for (int fm = 0; fm < 4; fm++)
        aV[fm] = *(const u64x2*)&sA[buf][(wm * 64 + fm * 16 + frow) * 128 + ph * 16];
#pragma unroll
      for (int fn = 0; fn < 2; fn++)
        bV[fn] = *(const u64x2*)&sB[buf][(wn * 32 + fn * 16 + frow) * 128 + ph * 16];
#pragma unroll
      for (int fm = 0; fm < 4; fm++)
#pragma unroll
        for (int fn = 0; fn < 2; fn++) {
          acc[fm][fn] = __builtin_amdgcn_mfma_f32_16x16x32_fp8_fp8(
              (long long)aV[fm].x, (long long)bV[fn].x, acc[fm][fn], 0, 0, 0);
          acc[fm][fn] = __builtin_amdgcn_mfma_f32_16x16x32_fp8_fp8(
              (long long)aV[fm].y, (long long)bV[fn].y, acc[fm][fn], 0, 0, 0);
        }
    }
  };

  stage(0, 0);
  for (int kb = 0; kb < nkb; kb++) {
    asm volatile("" ::: "memory");
    __builtin_amdgcn_s_barrier();                      // BARRIER A: buf free to overwrite
    asm volatile("" ::: "memory");
    if (kb + 1 < nkb) {
      stage((kb + 1) & 1, kb + 1);                     // 4 loads in flight across barrier
      asm volatile("s_waitcnt vmcnt(4)" ::: "memory"); // current tile's 4 complete
    } else {
      asm volatile("s_waitcnt vmcnt(0)" ::: "memory"); // last tile: drain
    }
    __builtin_amdgcn_s_barrier();                      // BARRIER B: tile resident
    asm volatile("" ::: "memory");
    compute(kb & 1);
  }

  // fused epilogue: C/D layout col = lane&15, row = (lane>>4)*4 + reg  [HW-verified].
  // du bytes from LAST A-tile in LDS: byte (rt,c) at rt*128 + ((c>>4)^(rt&7))*16 + (c&15).
  const int lastBuf = (nkb - 1) & 1;
  float psum = 0.f;
#pragma unroll
  for (int fm = 0; fm < 4; fm++) {
#pragma unroll
    for (int fn = 0; fn < 2; fn++) {
      const int c = wn * 32 + fn * 16 + frow;    // col within tile
      const int icol = col0 + c;                 // du index i; output position n = i+1
      if (icol < 1023) {
#pragma unroll
        for (int reg = 0; reg < 4; reg++) {
          const int rt = wm * 64 + fm * 16 + g4 * 4 + reg;   // row within tile
          float frac = COEF * acc[fm][fn][reg];
          float dui = fp8_dec(sA[lastBuf][rt * 128 + (((c >> 4) ^ (rt & 7)) << 4) + (c & 15)]);
          float ut;
          if (icol == 1022) {
            ut = dui;                            // n = N-1 edge: u_t = du[N-2]
          } else {
            float dui1;
            if (c == 127) {                      // tile edge: one global byte
              dui1 = fp8_dec(du8[(size_t)(row0 + rt) * 1024 + icol + 1]);
            } else {
              const int c1 = c + 1;
              dui1 = fp8_dec(sA[lastBuf][rt * 128 + (((c1 >> 4) ^ (rt & 7)) << 4) + (c1 & 15)]);
            }
            ut = 0.5f * (dui + dui1);            // central difference
          }
          float res = ut - frac;
          psum += res * res;
        }
      }
    }
  }

#pragma unroll
  for (int off = 32; off > 0; off >>= 1) psum += __shfl_down(psum, off, 64);
  if (lane == 0) wsum[w] = psum;

  // pre-reduce this block's 16-row slice of dpart/ppart (wave 0, one cache line each)
  float ds_ = 0.f, ps_ = 0.f;
  if (w == 0) {
    if (t < 16) { ds_ = dpart[bid * 16 + t]; ps_ = ppart[bid * 16 + t]; }
#pragma unroll
    for (int off = 8; off > 0; off >>= 1) {
      ds_ += __shfl_down(ds_, off, 64);
      ps_ += __shfl_down(ps_, off, 64);
    }
  }
  __syncthreads();
  if (t == 0) {
    float s = 0.f;
#pragma unroll
    for (int i = 0; i < 8; i++) s += wsum[i];
    gpart[bid] = s + ps_;
    gpart[512 + bid] = ds_;
  }
}

// ---- phase 3 body: reduce 1024 partials -> 3 outputs (one 512-thread block) ----
__device__ __forceinline__ void finalize_body(int t, const float* __restrict__ gpart,
                                              float* __restrict__ out) {
  __shared__ float sp8[8], sd8[8];
  const int w = t >> 6, lane = t & 63;
  float ps = gpart[t];
  float ds = gpart[512 + t];
#pragma unroll
  for (int off = 32; off > 0; off >>= 1) {
    ps += __shfl_down(ps, off, 64);
    ds += __shfl_down(ds, off, 64);
  }
  if (lane == 0) { sp8[w] = ps; sd8[w] = ds; }
  __syncthreads();
  if (t == 0) {
    float pst = 0.f, dst = 0.f;
#pragma unroll
    for (int i = 0; i < 8; i++) { pst += sp8[i]; dst += sd8[i]; }
    float data = dst * INV_COUNT;
    float phys = pst * INV_COUNT;
    out[0] = data + 0.1f * phys;
    out[1] = data;
    out[2] = phys;
  }
}

// ---- fused cooperative kernel: prep -> grid.sync -> gemm -> grid.sync -> finalize ----
__launch_bounds__(512, 4)
__global__ void fused(const float* __restrict__ up, const float* __restrict__ utr,
                      unsigned char* __restrict__ du8, unsigned char* __restrict__ Mt8,
                      float* __restrict__ dpart, float* __restrict__ ppart,
                      float* __restrict__ gpart, float* __restrict__ out) {
  const int bid = blockIdx.x, t = threadIdx.x;
  prep_body(bid, t, up, utr, du8, Mt8, dpart, ppart);
  cg::this_grid().sync();
  gemm_body(bid, t, du8, Mt8, gpart, dpart, ppart);
  cg::this_grid().sync();
  if (bid == 0) finalize_body(t, gpart, out);
}

// ---- fallback: same bodies as 3 plain kernels (if cooperative launch unavailable) ----
__launch_bounds__(512, 4)
__global__ void prep_k(const float* __restrict__ up, const float* __restrict__ utr,
                       unsigned char* __restrict__ du8, unsigned char* __restrict__ Mt8,
                       float* __restrict__ dpart, float* __restrict__ ppart) {
  prep_body(blockIdx.x, threadIdx.x, up, utr, du8, Mt8, dpart, ppart);
}
__launch_bounds__(512, 4)
__global__ void gemm_k(const unsigned char* __restrict__ du8,
                       const unsigned char* __restrict__ Mt8,
                       float* __restrict__ gpart,
                       const float* __restrict__ dpart, const float* __restrict__ ppart) {
  gemm_body(blockIdx.x, threadIdx.x, du8, Mt8, gpart, dpart, ppart);
}
__global__ void fin_k(const float* __restrict__ gpart, float* __restrict__ out) {
  finalize_body(threadIdx.x, gpart, out);
}

extern "C" void kernel_launch(void* const* d_in, const int* in_sizes, int n_in,
                              void* d_out, int out_size, void* d_ws, size_t ws_size,
                              hipStream_t stream) {
  const float* u_pred = (const float*)d_in[0];
  const float* u_true = (const float*)d_in[1];
  float* out = (float*)d_out;

  char* ws = (char*)d_ws;
  float* dpart = (float*)ws;                                    // 8192 floats (32 KiB)
  float* ppart = (float*)(ws + 32768);                          // 8192 floats (32 KiB)
  float* gpart = (float*)(ws + 65536);                          // 1024 floats (4 KiB)
  unsigned char* Mt8 = (unsigned char*)(ws + 131072);           // 1024*1024 = 1 MiB
  unsigned char* du8 = (unsigned char*)(ws + 131072 + 1048576); // 8192*1024 = 8 MiB

  void* args[] = {(void*)&u_pred, (void*)&u_true, (void*)&du8, (void*)&Mt8,
                  (void*)&dpart, (void*)&ppart, (void*)&gpart, (void*)&out};
  hipError_t err = hipLaunchCooperativeKernel((void*)fused, dim3(512), dim3(512),
                                              args, 0, stream);
  if (err != hipSuccess) {
    // fallback: 3 plain launches (stream ordering provides the syncs)
    prep_k<<<512, 512, 0, stream>>>(u_pred, u_true, du8, Mt8, dpart, ppart);
    gemm_k<<<512, 512, 0, stream>>>(du8, Mt8, gpart, dpart, ppart);
    fin_k<<<1, 512, 0, stream>>>(gpart, out);
  }
}

// Round 14
// 36.914 us; speedup vs baseline: 4.0373x; 4.0373x over previous
//
#include <hip/hip_runtime.h>
#include <hip/hip_bf16.h>

// Problem constants: B=32, T=256, N=1024 -> R = 8192 rows, K = N-1 = 1023 (padded to 1024)
// alpha = 0.5, b[m] = sqrt(m+1)-sqrt(m) = 1/(sqrt(m+1)+sqrt(m)), coef = sqrt(1023)/Gamma(1.5)
#define COEF 36.090511f
#define INV_COUNT (1.0f / 8388608.0f)   // 1 / (32*256*1024)

typedef __attribute__((ext_vector_type(4))) float f32x4;
typedef __attribute__((ext_vector_type(2))) unsigned long long u64x2;

typedef const __attribute__((address_space(1))) unsigned int* gas_ptr;
typedef __attribute__((address_space(3))) unsigned int* las_ptr;

__device__ __forceinline__ void load_lds16(const void* g, void* l) {
  __builtin_amdgcn_global_load_lds((gas_ptr)g, (las_ptr)l, 16, 0, 0);
}

// manual OCP e4m3fn decode (bias 7): exact
__device__ __forceinline__ float fp8_dec(unsigned int v) {
  const unsigned e = (v >> 3) & 0xF, m = v & 7;
  const int mant = e ? (8 + (int)m) : (int)m;
  const int ee = e ? (int)e : 1;
  float f = (float)mant * __int_as_float((ee + 117) << 23);  // mant * 2^(ee-10)
  return (v & 0x80) ? -f : f;
}

// prep blocks 0..8191: du8 = fp8(u_pred diffs), col 1023 = 0 pad; per-row partials.
// blocks 8192..8319: Mt8d = DEDUP'd Toeplitz B: 8 tiles [d][i'][j'], d = cb-kb,
//   entry = fp8(b[d*128 + i' - j']) (0 if negative). 128 KB total -> L2/L1-hot.
__global__ void prep(const float* __restrict__ up, const float* __restrict__ utr,
                     unsigned char* __restrict__ du8, unsigned char* __restrict__ Mt8d,
                     float* __restrict__ dpart, float* __restrict__ ppart) {
  const int t = threadIdx.x;      // 256 threads
  if (blockIdx.x >= 8192) {
    const int g = (blockIdx.x - 8192) * 1024 + t * 4;   // byte index into 128KB tile set
    const int d = g >> 14;            // tile 0..7
    const int rem = g & 16383;
    const int ip = rem >> 7;          // i' 0..127
    const int j0 = rem & 127;         // j' byte 0..124 (multiple of 4)
    float v[4];
#pragma unroll
    for (int e = 0; e < 4; e++) {
      int m = d * 128 + ip - (j0 + e);
      v[e] = 0.f;
      if (m >= 0) { float fm_ = (float)m; v[e] = 1.0f / (sqrtf(fm_ + 1.f) + sqrtf(fm_)); }
    }
    int w_ = __builtin_amdgcn_cvt_pk_fp8_f32(v[0], v[1], 0, false);
    w_ = __builtin_amdgcn_cvt_pk_fp8_f32(v[2], v[3], w_, true);
    *(unsigned int*)(Mt8d + g) = (unsigned int)w_;
    return;
  }

  const int r = blockIdx.x;       // 8192 rows
  const int j0 = t * 4;
  const float* rowp = up + (size_t)r * 1024;

  f32x4 a = *(const f32x4*)(rowp + j0);
  f32x4 b = *(const f32x4*)(utr + (size_t)r * 1024 + j0);

  // a4 = a[0] of lane+1 (next 4-chunk's first elem); wave-edge lanes load scalar
  float a4 = __shfl_down(a[0], 1, 64);
  if ((t & 63) == 63 && t < 255) a4 = rowp[j0 + 4];

  float d0 = a[1] - a[0];
  float d1 = a[2] - a[1];
  float d2 = a[3] - a[2];
  float d3 = (t < 255) ? (a4 - a[3]) : 0.f;   // du[1023] = 0 pad

  int w_ = __builtin_amdgcn_cvt_pk_fp8_f32(d0, d1, 0, false);
  w_ = __builtin_amdgcn_cvt_pk_fp8_f32(d2, d3, w_, true);
  *(unsigned int*)(du8 + (size_t)r * 1024 + j0) = (unsigned int)w_;

  float e0 = a[0] - b[0], e1 = a[1] - b[1], e2 = a[2] - b[2], e3 = a[3] - b[3];
  float dsum = e0 * e0 + e1 * e1 + e2 * e2 + e3 * e3;

#pragma unroll
  for (int off = 32; off > 0; off >>= 1) dsum += __shfl_down(dsum, off, 64);
  __shared__ float ws4[4];
  const int lane = t & 63, w = t >> 6;
  if (lane == 0) ws4[w] = dsum;
  __syncthreads();
  if (t == 0) {
    dpart[r] = ws4[0] + ws4[1] + ws4[2] + ws4[3];
    ppart[r] = d0 * d0;   // physics residual at n=0: u_t = du[r,0], frac_lap[0] = 0
  }
}

// Y[r,i] = sum_j du[r,j] * b[i-j]; fused epilogue: resid = u_t - COEF*Y, psum += resid^2.
// fp8 GEMM: 128x128 tile, BK=128 bytes, 8 waves (512 thr, wave quadrant 64x32), 16 waves/CU.
// Double-buffered LDS, XOR quad-swizzle, counted vmcnt(4), XCD+triangular-robust map.
// B staged from the 8-tile dedup'd Toeplitz (d = cb-kb) -> whole B working set L1/L2-hot.
// Epilogue: du from LAST A-tile in LDS; neighbor byte via __shfl_down (halves LDS reads).
__launch_bounds__(512, 4)
__global__ void gemm(const unsigned char* __restrict__ du8,
                     const unsigned char* __restrict__ Mt8d,
                     float* __restrict__ gpart,
                     const float* __restrict__ dpart, const float* __restrict__ ppart) {
  __shared__ unsigned char sA[2][16384];   // [128 rows][128 k-bytes], quad-swizzled
  __shared__ unsigned char sB[2][16384];
  __shared__ float wsum[8];

  const int t = threadIdx.x;      // 512 threads = 8 waves
  const int w = t >> 6;
  const int lane = t & 63;

  const int bid = blockIdx.x;      // 0..511
  const int xcd = bid & 7;
  const int local = bid >> 3;      // 0..63
  const int e = local & 1;
  const int j = local >> 1;        // 0..31
  const int h = (j < 16) ? (j & 7) : 7 - (j & 7);
  const int cb = e ? 7 - h : h;                 // pairs (2k,2k+1) and (k,k+32) both sum to 7
  const int rb = xcd * 8 + (((j >> 3) << 1) | e);   // bijective with cb per XCD
  const int row0 = rb * 128;
  const int col0 = cb * 128;
  const int nkb = cb + 1;          // K-blocks of 128 bytes (triangular skip)

  const f32x4 vzero = {0.f, 0.f, 0.f, 0.f};
  f32x4 acc[4][2];
#pragma unroll
  for (int i = 0; i < 4; i++)
#pragma unroll
    for (int jj = 0; jj < 2; jj++) acc[i][jj] = vzero;

  // staging: 512 threads x 16B = 8KB/call -> 2 calls per 16KB tile.
  // thread t covers (row = t>>3, phys quad = t&7); src quad = phys ^ (row&7)
  const int srow = t >> 3;                            // 0..63
  const int sq = ((t & 7) ^ (srow & 7)) * 16;         // pre-swizzled source byte col
  const unsigned char* gA0 = du8 + (size_t)(row0 + srow) * 1024 + sq;
  const unsigned char* gB0 = Mt8d + srow * 128 + sq;  // + d*16384 per iter

  auto stage = [&](int buf, int kb) {
    const int kc = kb * 128;
    const size_t doff = (size_t)(cb - kb) * 16384;
#pragma unroll
    for (int l = 0; l < 2; l++)
      load_lds16(gA0 + (size_t)l * 64 * 1024 + kc, (void*)&sA[buf][l * 8192 + t * 16]);
#pragma unroll
    for (int l = 0; l < 2; l++)
      load_lds16(gB0 + doff + l * 64 * 128, (void*)&sB[buf][l * 8192 + t * 16]);
  };

  const int wm = w >> 2, wn = w & 3;     // wave quadrant: rows wm*64, cols wn*32
  const int frow = lane & 15;
  const int g4 = lane >> 4;              // lane's k-owner group 0..3

  auto compute = [&](int buf) {
#pragma unroll
    for (int p = 0; p < 2; p++) {
      const int lq = g4 * 2 + p;               // logical quad
      const int ph = lq ^ (frow & 7);          // physical quad (swizzle)
      u64x2 aV[4], bV[2];
#pragma unroll
      for (int fm = 0; fm < 4; fm++)
        aV[fm] = *(const u64x2*)&sA[buf][(wm * 64 + fm * 16 + frow) * 128 + ph * 16];
#pragma unroll
      for (int fn = 0; fn < 2; fn++)
        bV[fn] = *(const u64x2*)&sB[buf][(wn * 32 + fn * 16 + frow) * 128 + ph * 16];
#pragma unroll
      for (int fm = 0; fm < 4; fm++)
#pragma unroll
        for (int fn = 0; fn < 2; fn++) {
          acc[fm][fn] = __builtin_amdgcn_mfma_f32_16x16x32_fp8_fp8(
              (long long)aV[fm].x, (long long)bV[fn].x, acc[fm][fn], 0, 0, 0);
          acc[fm][fn] = __builtin_amdgcn_mfma_f32_16x16x32_fp8_fp8(
              (long long)aV[fm].y, (long long)bV[fn].y, acc[fm][fn], 0, 0, 0);
        }
    }
  };

  stage(0, 0);
  for (int kb = 0; kb < nkb; kb++) {
    asm volatile("" ::: "memory");
    __builtin_amdgcn_s_barrier();                      // BARRIER A: buf free to overwrite
    asm volatile("" ::: "memory");
    if (kb + 1 < nkb) {
      stage((kb + 1) & 1, kb + 1);                     // 4 loads in flight across barrier
      asm volatile("s_waitcnt vmcnt(4)" ::: "memory"); // current tile's 4 complete
    } else {
      asm volatile("s_waitcnt vmcnt(0)" ::: "memory"); // last tile: drain
    }
    __builtin_amdgcn_s_barrier();                      // BARRIER B: tile resident
    asm volatile("" ::: "memory");
    compute(kb & 1);
  }

  // fused epilogue: C/D layout col = lane&15, row = (lane>>4)*4 + reg  [HW-verified].
  // du bytes from LAST A-tile in LDS: byte (rt,c) at rt*128 + ((c>>4)^(rt&7))*16 + (c&15).
  // Neighbor byte (c+1) comes from the next lane's dui via shfl (same rt: lane = g4*16+frow,
  // shfl_down 1 stays in-group for frow<15); frow==15 lanes read LDS/global explicitly.
  const int lastBuf = (nkb - 1) & 1;
  float psum = 0.f;
#pragma unroll
  for (int fm = 0; fm < 4; fm++) {
#pragma unroll
    for (int fn = 0; fn < 2; fn++) {
      const int c = wn * 32 + fn * 16 + frow;    // col within tile
      const int icol = col0 + c;                 // du index i; output position n = i+1
#pragma unroll
      for (int reg = 0; reg < 4; reg++) {
        const int rt = wm * 64 + fm * 16 + g4 * 4 + reg;   // row within tile
        float dui = fp8_dec(sA[lastBuf][rt * 128 + (((c >> 4) ^ (rt & 7)) << 4) + (c & 15)]);
        float dnext = __shfl_down(dui, 1, 64);             // dui of (rt, c+1) for frow<15
        if (frow == 15) {
          if (c == 127) {                                  // tile edge: global byte (cb<7)
            dnext = (icol < 1022) ? fp8_dec(du8[(size_t)(row0 + rt) * 1024 + icol + 1]) : 0.f;
          } else {
            const int c1 = c + 1;
            dnext = fp8_dec(sA[lastBuf][rt * 128 + (((c1 >> 4) ^ (rt & 7)) << 4) + (c1 & 15)]);
          }
        }
        if (icol < 1023) {
          float frac = COEF * acc[fm][fn][reg];
          float ut = (icol == 1022) ? dui : 0.5f * (dui + dnext);
          float res = ut - frac;
          psum += res * res;
        }
      }
    }
  }

#pragma unroll
  for (int off = 32; off > 0; off >>= 1) psum += __shfl_down(psum, off, 64);
  if (lane == 0) wsum[w] = psum;

  // pre-reduce this block's 16-row slice of dpart/ppart (wave 0, one cache line each)
  float ds_ = 0.f, ps_ = 0.f;
  if (w == 0) {
    if (t < 16) { ds_ = dpart[bid * 16 + t]; ps_ = ppart[bid * 16 + t]; }
#pragma unroll
    for (int off = 8; off > 0; off >>= 1) {
      ds_ += __shfl_down(ds_, off, 64);
      ps_ += __shfl_down(ps_, off, 64);
    }
  }
  __syncthreads();
  if (t == 0) {
    float s = 0.f;
#pragma unroll
    for (int i = 0; i < 8; i++) s += wsum[i];
    gpart[bid] = s + ps_;
    gpart[512 + bid] = ds_;
  }
}

// Single-block reduction of 1024 partials -> 3 outputs.
__global__ void finalize(const float* __restrict__ gpart, float* __restrict__ out) {
  const int t = threadIdx.x;    // 256 threads
  float ds = 0.f, ps = 0.f;
  for (int i = t; i < 512; i += 256) { ps += gpart[i]; ds += gpart[512 + i]; }

#pragma unroll
  for (int off = 32; off > 0; off >>= 1) {
    ds += __shfl_down(ds, off, 64);
    ps += __shfl_down(ps, off, 64);
  }
  __shared__ float sd[4], sp[4];
  const int lane = t & 63, w = t >> 6;
  if (lane == 0) { sd[w] = ds; sp[w] = ps; }
  __syncthreads();
  if (t == 0) {
    float data = (sd[0] + sd[1] + sd[2] + sd[3]) * INV_COUNT;
    float phys = (sp[0] + sp[1] + sp[2] + sp[3]) * INV_COUNT;
    out[0] = data + 0.1f * phys;
    out[1] = data;
    out[2] = phys;
  }
}

extern "C" void kernel_launch(void* const* d_in, const int* in_sizes, int n_in,
                              void* d_out, int out_size, void* d_ws, size_t ws_size,
                              hipStream_t stream) {
  const float* u_pred = (const float*)d_in[0];
  const float* u_true = (const float*)d_in[1];
  float* out = (float*)d_out;

  char* ws = (char*)d_ws;
  float* dpart = (float*)ws;                                    // 8192 floats (32 KiB)
  float* ppart = (float*)(ws + 32768);                          // 8192 floats (32 KiB)
  float* gpart = (float*)(ws + 65536);                          // 1024 floats (4 KiB)
  unsigned char* Mt8d = (unsigned char*)(ws + 131072);          // 8 tiles * 16 KiB = 128 KiB
  unsigned char* du8 = (unsigned char*)(ws + 131072 + 1048576); // 8192*1024 = 8 MiB

  prep<<<8320, 256, 0, stream>>>(u_pred, u_true, du8, Mt8d, dpart, ppart);
  gemm<<<512, 512, 0, stream>>>(du8, Mt8d, gpart, dpart, ppart);
  finalize<<<1, 256, 0, stream>>>(gpart, out);
}

// Round 15
// 36.345 us; speedup vs baseline: 4.1005x; 1.0157x over previous
//
#include <hip/hip_runtime.h>
#include <hip/hip_bf16.h>

// Problem constants: B=32, T=256, N=1024 -> R = 8192 rows, K = N-1 = 1023 (padded to 1024)
// alpha = 0.5, b[m] = sqrt(m+1)-sqrt(m) = 1/(sqrt(m+1)+sqrt(m)), coef = sqrt(1023)/Gamma(1.5)
#define COEF 36.090511f
#define INV_COUNT (1.0f / 8388608.0f)   // 1 / (32*256*1024)

typedef __attribute__((ext_vector_type(4))) float f32x4;
typedef __attribute__((ext_vector_type(2))) unsigned long long u64x2;

typedef const __attribute__((address_space(1))) unsigned int* gas_ptr;
typedef __attribute__((address_space(3))) unsigned int* las_ptr;

__device__ __forceinline__ void load_lds16(const void* g, void* l) {
  __builtin_amdgcn_global_load_lds((gas_ptr)g, (las_ptr)l, 16, 0, 0);
}

// manual OCP e4m3fn decode (bias 7): exact
__device__ __forceinline__ float fp8_dec(unsigned int v) {
  const unsigned e = (v >> 3) & 0xF, m = v & 7;
  const int mant = e ? (8 + (int)m) : (int)m;
  const int ee = e ? (int)e : 1;
  float f = (float)mant * __int_as_float((ee + 117) << 23);  // mant * 2^(ee-10)
  return (v & 0x80) ? -f : f;
}

// prep blocks 0..8191: du8 rows with XCD-ALIGNED mapping r = (b&7)*1024 + (b>>3):
// block b lands on XCD b&7 (round-robin) and writes a row of the du8 panel that XCD's
// gemm blocks will read -> panel (1MB) stays dirty-hot in the local L2 across kernels.
// blocks 8192..8319: Mt8d = dedup'd Toeplitz B (8 tiles of 16KB, d = cb-kb).
__global__ void prep(const float* __restrict__ up, const float* __restrict__ utr,
                     unsigned char* __restrict__ du8, unsigned char* __restrict__ Mt8d,
                     float* __restrict__ dpart, float* __restrict__ ppart) {
  const int t = threadIdx.x;      // 256 threads
  if (blockIdx.x >= 8192) {
    const int g = (blockIdx.x - 8192) * 1024 + t * 4;   // byte index into 128KB tile set
    const int d = g >> 14;            // tile 0..7
    const int rem = g & 16383;
    const int ip = rem >> 7;          // i' 0..127
    const int j0 = rem & 127;         // j' byte
    float v[4];
#pragma unroll
    for (int e = 0; e < 4; e++) {
      int m = d * 128 + ip - (j0 + e);
      v[e] = 0.f;
      if (m >= 0) { float fm_ = (float)m; v[e] = 1.0f / (sqrtf(fm_ + 1.f) + sqrtf(fm_)); }
    }
    int w_ = __builtin_amdgcn_cvt_pk_fp8_f32(v[0], v[1], 0, false);
    w_ = __builtin_amdgcn_cvt_pk_fp8_f32(v[2], v[3], w_, true);
    *(unsigned int*)(Mt8d + g) = (unsigned int)w_;
    return;
  }

  const int r = ((blockIdx.x & 7) << 10) | (blockIdx.x >> 3);   // XCD-aligned row
  const int j0 = t * 4;
  const float* rowp = up + (size_t)r * 1024;

  f32x4 a = *(const f32x4*)(rowp + j0);
  f32x4 b = *(const f32x4*)(utr + (size_t)r * 1024 + j0);

  // a4 = a[0] of lane+1 (next 4-chunk's first elem); wave-edge lanes load scalar
  float a4 = __shfl_down(a[0], 1, 64);
  if ((t & 63) == 63 && t < 255) a4 = rowp[j0 + 4];

  float d0 = a[1] - a[0];
  float d1 = a[2] - a[1];
  float d2 = a[3] - a[2];
  float d3 = (t < 255) ? (a4 - a[3]) : 0.f;   // du[1023] = 0 pad

  int w_ = __builtin_amdgcn_cvt_pk_fp8_f32(d0, d1, 0, false);
  w_ = __builtin_amdgcn_cvt_pk_fp8_f32(d2, d3, w_, true);
  *(unsigned int*)(du8 + (size_t)r * 1024 + j0) = (unsigned int)w_;

  float e0 = a[0] - b[0], e1 = a[1] - b[1], e2 = a[2] - b[2], e3 = a[3] - b[3];
  float dsum = e0 * e0 + e1 * e1 + e2 * e2 + e3 * e3;

#pragma unroll
  for (int off = 32; off > 0; off >>= 1) dsum += __shfl_down(dsum, off, 64);
  __shared__ float ws4[4];
  const int lane = t & 63, w = t >> 6;
  if (lane == 0) ws4[w] = dsum;
  __syncthreads();
  if (t == 0) {
    dpart[r] = ws4[0] + ws4[1] + ws4[2] + ws4[3];
    ppart[r] = d0 * d0;   // physics residual at n=0: u_t = du[r,0], frac_lap[0] = 0
  }
}

// Y[r,i] = sum_j du[r,j] * b[i-j]; fused epilogue: resid = u_t - COEF*Y, psum += resid^2.
// fp8 GEMM: 128x128 tile, BK=128 bytes, 8 waves (wave quadrant 64x32), 16 waves/CU.
// Double-buffered LDS, XOR quad-swizzle, counted vmcnt(4), XCD+triangular-robust map.
// A-panel now L2-LOCAL (prep writes with matching XCD map). B from 8-tile dedup (L1-hot).
// Epilogue: du from LAST A-tile in LDS; neighbor byte via __shfl_down.
__launch_bounds__(512, 4)
__global__ void gemm(const unsigned char* __restrict__ du8,
                     const unsigned char* __restrict__ Mt8d,
                     float* __restrict__ gpart,
                     const float* __restrict__ dpart, const float* __restrict__ ppart) {
  __shared__ unsigned char sA[2][16384];   // [128 rows][128 k-bytes], quad-swizzled
  __shared__ unsigned char sB[2][16384];
  __shared__ float wsum[8];

  const int t = threadIdx.x;      // 512 threads = 8 waves
  const int w = t >> 6;
  const int lane = t & 63;

  const int bid = blockIdx.x;      // 0..511
  const int xcd = bid & 7;
  const int local = bid >> 3;      // 0..63
  const int e = local & 1;
  const int j = local >> 1;        // 0..31
  const int h = (j < 16) ? (j & 7) : 7 - (j & 7);
  const int cb = e ? 7 - h : h;                 // pairs (2k,2k+1) and (k,k+32) both sum to 7
  const int rb = xcd * 8 + (((j >> 3) << 1) | e);   // bijective with cb per XCD
  const int row0 = rb * 128;
  const int col0 = cb * 128;
  const int nkb = cb + 1;          // K-blocks of 128 bytes (triangular skip)

  const f32x4 vzero = {0.f, 0.f, 0.f, 0.f};
  f32x4 acc[4][2];
#pragma unroll
  for (int i = 0; i < 4; i++)
#pragma unroll
    for (int jj = 0; jj < 2; jj++) acc[i][jj] = vzero;

  // staging: 512 threads x 16B = 8KB/call -> 2 calls per 16KB tile.
  const int srow = t >> 3;                            // 0..63
  const int sq = ((t & 7) ^ (srow & 7)) * 16;         // pre-swizzled source byte col
  const unsigned char* gA0 = du8 + (size_t)(row0 + srow) * 1024 + sq;
  const unsigned char* gB0 = Mt8d + srow * 128 + sq;  // + d*16384 per iter

  auto stage = [&](int buf, int kb) {
    const int kc = kb * 128;
    const size_t doff = (size_t)(cb - kb) * 16384;
#pragma unroll
    for (int l = 0; l < 2; l++)
      load_lds16(gA0 + (size_t)l * 64 * 1024 + kc, (void*)&sA[buf][l * 8192 + t * 16]);
#pragma unroll
    for (int l = 0; l < 2; l++)
      load_lds16(gB0 + doff + l * 64 * 128, (void*)&sB[buf][l * 8192 + t * 16]);
  };

  const int wm = w >> 2, wn = w & 3;     // wave quadrant: rows wm*64, cols wn*32
  const int frow = lane & 15;
  const int g4 = lane >> 4;              // lane's k-owner group 0..3

  auto compute = [&](int buf) {
#pragma unroll
    for (int p = 0; p < 2; p++) {
      const int lq = g4 * 2 + p;               // logical quad
      const int ph = lq ^ (frow & 7);          // physical quad (swizzle)
      u64x2 aV[4], bV[2];
#pragma unroll
      for (int fm = 0; fm < 4; fm++)
        aV[fm] = *(const u64x2*)&sA[buf][(wm * 64 + fm * 16 + frow) * 128 + ph * 16];
#pragma unroll
      for (int fn = 0; fn < 2; fn++)
        bV[fn] = *(const u64x2*)&sB[buf][(wn * 32 + fn * 16 + frow) * 128 + ph * 16];
#pragma unroll
      for (int fm = 0; fm < 4; fm++)
#pragma unroll
        for (int fn = 0; fn < 2; fn++) {
          acc[fm][fn] = __builtin_amdgcn_mfma_f32_16x16x32_fp8_fp8(
              (long long)aV[fm].x, (long long)bV[fn].x, acc[fm][fn], 0, 0, 0);
          acc[fm][fn] = __builtin_amdgcn_mfma_f32_16x16x32_fp8_fp8(
              (long long)aV[fm].y, (long long)bV[fn].y, acc[fm][fn], 0, 0, 0);
        }
    }
  };

  stage(0, 0);
  for (int kb = 0; kb < nkb; kb++) {
    asm volatile("" ::: "memory");
    __builtin_amdgcn_s_barrier();                      // BARRIER A: buf free to overwrite
    asm volatile("" ::: "memory");
    if (kb + 1 < nkb) {
      stage((kb + 1) & 1, kb + 1);                     // 4 loads in flight across barrier
      asm volatile("s_waitcnt vmcnt(4)" ::: "memory"); // current tile's 4 complete
    } else {
      asm volatile("s_waitcnt vmcnt(0)" ::: "memory"); // last tile: drain
    }
    __builtin_amdgcn_s_barrier();                      // BARRIER B: tile resident
    asm volatile("" ::: "memory");
    compute(kb & 1);
  }

  // fused epilogue: C/D layout col = lane&15, row = (lane>>4)*4 + reg  [HW-verified].
  // du bytes from LAST A-tile in LDS: byte (rt,c) at rt*128 + ((c>>4)^(rt&7))*16 + (c&15).
  // Neighbor byte (c+1) via __shfl_down within the 16-lane group; frow==15 reads explicitly.
  const int lastBuf = (nkb - 1) & 1;
  float psum = 0.f;
#pragma unroll
  for (int fm = 0; fm < 4; fm++) {
#pragma unroll
    for (int fn = 0; fn < 2; fn++) {
      const int c = wn * 32 + fn * 16 + frow;    // col within tile
      const int icol = col0 + c;                 // du index i; output position n = i+1
#pragma unroll
      for (int reg = 0; reg < 4; reg++) {
        const int rt = wm * 64 + fm * 16 + g4 * 4 + reg;   // row within tile
        float dui = fp8_dec(sA[lastBuf][rt * 128 + (((c >> 4) ^ (rt & 7)) << 4) + (c & 15)]);
        float dnext = __shfl_down(dui, 1, 64);             // dui of (rt, c+1) for frow<15
        if (frow == 15) {
          if (c == 127) {                                  // tile edge: global byte (cb<7)
            dnext = (icol < 1022) ? fp8_dec(du8[(size_t)(row0 + rt) * 1024 + icol + 1]) : 0.f;
          } else {
            const int c1 = c + 1;
            dnext = fp8_dec(sA[lastBuf][rt * 128 + (((c1 >> 4) ^ (rt & 7)) << 4) + (c1 & 15)]);
          }
        }
        if (icol < 1023) {
          float frac = COEF * acc[fm][fn][reg];
          float ut = (icol == 1022) ? dui : 0.5f * (dui + dnext);
          float res = ut - frac;
          psum += res * res;
        }
      }
    }
  }

#pragma unroll
  for (int off = 32; off > 0; off >>= 1) psum += __shfl_down(psum, off, 64);
  if (lane == 0) wsum[w] = psum;

  // pre-reduce this block's 16-row slice of dpart/ppart (wave 0, one cache line each)
  float ds_ = 0.f, ps_ = 0.f;
  if (w == 0) {
    if (t < 16) { ds_ = dpart[bid * 16 + t]; ps_ = ppart[bid * 16 + t]; }
#pragma unroll
    for (int off = 8; off > 0; off >>= 1) {
      ds_ += __shfl_down(ds_, off, 64);
      ps_ += __shfl_down(ps_, off, 64);
    }
  }
  __syncthreads();
  if (t == 0) {
    float s = 0.f;
#pragma unroll
    for (int i = 0; i < 8; i++) s += wsum[i];
    gpart[bid] = s + ps_;
    gpart[512 + bid] = ds_;
  }
}

// Single-block reduction of 1024 partials -> 3 outputs.
__global__ void finalize(const float* __restrict__ gpart, float* __restrict__ out) {
  const int t = threadIdx.x;    // 256 threads
  float ds = 0.f, ps = 0.f;
  for (int i = t; i < 512; i += 256) { ps += gpart[i]; ds += gpart[512 + i]; }

#pragma unroll
  for (int off = 32; off > 0; off >>= 1) {
    ds += __shfl_down(ds, off, 64);
    ps += __shfl_down(ps, off, 64);
  }
  __shared__ float sd[4], sp[4];
  const int lane = t & 63, w = t >> 6;
  if (lane == 0) { sd[w] = ds; sp[w] = ps; }
  __syncthreads();
  if (t == 0) {
    float data = (sd[0] + sd[1] + sd[2] + sd[3]) * INV_COUNT;
    float phys = (sp[0] + sp[1] + sp[2] + sp[3]) * INV_COUNT;
    out[0] = data + 0.1f * phys;
    out[1] = data;
    out[2] = phys;
  }
}

extern "C" void kernel_launch(void* const* d_in, const int* in_sizes, int n_in,
                              void* d_out, int out_size, void* d_ws, size_t ws_size,
                              hipStream_t stream) {
  const float* u_pred = (const float*)d_in[0];
  const float* u_true = (const float*)d_in[1];
  float* out = (float*)d_out;

  char* ws = (char*)d_ws;
  float* dpart = (float*)ws;                                    // 8192 floats (32 KiB)
  float* ppart = (float*)(ws + 32768);                          // 8192 floats (32 KiB)
  float* gpart = (float*)(ws + 65536);                          // 1024 floats (4 KiB)
  unsigned char* Mt8d = (unsigned char*)(ws + 131072);          // 8 tiles * 16 KiB = 128 KiB
  unsigned char* du8 = (unsigned char*)(ws + 131072 + 1048576); // 8192*1024 = 8 MiB

  prep<<<8320, 256, 0, stream>>>(u_pred, u_true, du8, Mt8d, dpart, ppart);
  gemm<<<512, 512, 0, stream>>>(du8, Mt8d, gpart, dpart, ppart);
  finalize<<<1, 256, 0, stream>>>(gpart, out);
}

// Round 16
// 34.881 us; speedup vs baseline: 4.2726x; 1.0420x over previous
//
#include <hip/hip_runtime.h>
#include <hip/hip_bf16.h>

// Problem constants: B=32, T=256, N=1024 -> R = 8192 rows, K = N-1 = 1023 (padded to 1024)
// alpha = 0.5, b[m] = sqrt(m+1)-sqrt(m) = 1/(sqrt(m+1)+sqrt(m)), coef = sqrt(1023)/Gamma(1.5)
#define COEF 36.090511f
#define INV_COUNT (1.0f / 8388608.0f)   // 1 / (32*256*1024)

typedef __attribute__((ext_vector_type(4))) float f32x4;
typedef __attribute__((ext_vector_type(2))) unsigned long long u64x2;

typedef const __attribute__((address_space(1))) unsigned int* gas_ptr;
typedef __attribute__((address_space(3))) unsigned int* las_ptr;

__device__ __forceinline__ void load_lds16(const void* g, void* l) {
  __builtin_amdgcn_global_load_lds((gas_ptr)g, (las_ptr)l, 16, 0, 0);
}

// manual OCP e4m3fn decode (bias 7): exact
__device__ __forceinline__ float fp8_dec(unsigned int v) {
  const unsigned e = (v >> 3) & 0xF, m = v & 7;
  const int mant = e ? (8 + (int)m) : (int)m;
  const int ee = e ? (int)e : 1;
  float f = (float)mant * __int_as_float((ee + 117) << 23);  // mant * 2^(ee-10)
  return (v & 0x80) ? -f : f;
}

// prep blocks 0..8191: du8 rows, XCD-aligned map r = (b&7)*1024 + (b>>3).
// blocks 8192..8319: Mt8d = dedup'd Toeplitz B (8 tiles of 16KB, d = cb-kb).
__global__ void prep(const float* __restrict__ up, const float* __restrict__ utr,
                     unsigned char* __restrict__ du8, unsigned char* __restrict__ Mt8d,
                     float* __restrict__ dpart, float* __restrict__ ppart) {
  const int t = threadIdx.x;      // 256 threads
  if (blockIdx.x >= 8192) {
    const int g = (blockIdx.x - 8192) * 1024 + t * 4;   // byte index into 128KB tile set
    const int d = g >> 14;            // tile 0..7
    const int rem = g & 16383;
    const int ip = rem >> 7;          // i' 0..127
    const int j0 = rem & 127;         // j' byte
    float v[4];
#pragma unroll
    for (int e = 0; e < 4; e++) {
      int m = d * 128 + ip - (j0 + e);
      v[e] = 0.f;
      if (m >= 0) { float fm_ = (float)m; v[e] = 1.0f / (sqrtf(fm_ + 1.f) + sqrtf(fm_)); }
    }
    int w_ = __builtin_amdgcn_cvt_pk_fp8_f32(v[0], v[1], 0, false);
    w_ = __builtin_amdgcn_cvt_pk_fp8_f32(v[2], v[3], w_, true);
    *(unsigned int*)(Mt8d + g) = (unsigned int)w_;
    return;
  }

  const int r = ((blockIdx.x & 7) << 10) | (blockIdx.x >> 3);   // XCD-aligned row
  const int j0 = t * 4;
  const float* rowp = up + (size_t)r * 1024;

  f32x4 a = *(const f32x4*)(rowp + j0);
  f32x4 b = *(const f32x4*)(utr + (size_t)r * 1024 + j0);

  float a4 = __shfl_down(a[0], 1, 64);
  if ((t & 63) == 63 && t < 255) a4 = rowp[j0 + 4];

  float d0 = a[1] - a[0];
  float d1 = a[2] - a[1];
  float d2 = a[3] - a[2];
  float d3 = (t < 255) ? (a4 - a[3]) : 0.f;   // du[1023] = 0 pad

  int w_ = __builtin_amdgcn_cvt_pk_fp8_f32(d0, d1, 0, false);
  w_ = __builtin_amdgcn_cvt_pk_fp8_f32(d2, d3, w_, true);
  *(unsigned int*)(du8 + (size_t)r * 1024 + j0) = (unsigned int)w_;

  float e0 = a[0] - b[0], e1 = a[1] - b[1], e2 = a[2] - b[2], e3 = a[3] - b[3];
  float dsum = e0 * e0 + e1 * e1 + e2 * e2 + e3 * e3;

#pragma unroll
  for (int off = 32; off > 0; off >>= 1) dsum += __shfl_down(dsum, off, 64);
  __shared__ float ws4[4];
  const int lane = t & 63, w = t >> 6;
  if (lane == 0) ws4[w] = dsum;
  __syncthreads();
  if (t == 0) {
    dpart[r] = ws4[0] + ws4[1] + ws4[2] + ws4[3];
    ppart[r] = d0 * d0;   // physics residual at n=0: u_t = du[r,0], frac_lap[0] = 0
  }
}

// Y[r,i] = sum_j du[r,j] * b[i-j]; fused epilogue: resid = u_t - COEF*Y, psum += resid^2.
// fp8 GEMM: 64x128 tile, BK=128 bytes, 8 waves (32x32 wave tile), 1024 blocks -> up to
// 32 waves/CU (2x R15). LDS 32KB: sA double-buffered + sB SINGLE (barrier A orders the
// overwrite; issue-order vmcnt(1) keeps A-prefetch in flight while draining B(k)+A(k)).
// XOR quad-swizzle, XCD map (bid&7), triangular cb uniform under 4-packs both orders.
__launch_bounds__(512, 8)
__global__ void gemm(const unsigned char* __restrict__ du8,
                     const unsigned char* __restrict__ Mt8d,
                     float* __restrict__ gpart,
                     const float* __restrict__ dpart, const float* __restrict__ ppart) {
  __shared__ unsigned char sA[2][8192];    // [64 rows][128 k-bytes], quad-swizzled
  __shared__ unsigned char sB[16384];      // [128 cols][128 k-bytes], single-buffered
  __shared__ float wsum[8];

  const int t = threadIdx.x;      // 512 threads = 8 waves
  const int w = t >> 6;
  const int lane = t & 63;

  const int bid = blockIdx.x;      // 0..1023
  const int xcd = bid & 7;
  const int local = bid >> 3;      // 0..127
  const int e = local & 1;
  const int j = local >> 1;        // 0..63
  const int h = (j < 32) ? (j & 7) : 7 - (j & 7);
  const int cb = e ? 7 - h : h;    // consecutive pairs AND +-32 j-pairs sum to 7
  const int r16 = (((j >> 3) & 3) << 2) | (((j >> 5) & 1) << 1) | e;   // bijective
  const int rb = xcd * 16 + r16;   // 0..127 (64-row tiles); XCD x owns rows [x*1024,+1024)
  const int row0 = rb * 64;
  const int col0 = cb * 128;
  const int nkb = cb + 1;          // K-blocks of 128 bytes (triangular skip)

  const f32x4 vzero = {0.f, 0.f, 0.f, 0.f};
  f32x4 acc[2][2];
#pragma unroll
  for (int i = 0; i < 2; i++)
#pragma unroll
    for (int jj = 0; jj < 2; jj++) acc[i][jj] = vzero;

  // staging: thread t covers (row = t>>3, phys quad = t&7); src quad = phys ^ (row&7)
  const int srow = t >> 3;                            // 0..63
  const int sq = ((t & 7) ^ (srow & 7)) * 16;         // pre-swizzled source byte col
  const unsigned char* gA0 = du8 + (size_t)(row0 + srow) * 1024 + sq;
  const unsigned char* gB0 = Mt8d + srow * 128 + sq;  // + d*16384 per iter

  auto stageA = [&](int buf, int kb) {                // 1 load: 64x128 = 8KB
    load_lds16(gA0 + kb * 128, (void*)&sA[buf][t * 16]);
  };
  auto stageB = [&](int kb) {                         // 2 loads: 128x128 = 16KB
    const size_t doff = (size_t)(cb - kb) * 16384;
#pragma unroll
    for (int l = 0; l < 2; l++)
      load_lds16(gB0 + doff + l * 64 * 128, (void*)&sB[l * 8192 + t * 16]);
  };

  const int wm = w >> 2, wn = w & 3;     // wave tile: rows wm*32, cols wn*32
  const int frow = lane & 15;
  const int g4 = lane >> 4;              // lane's k-owner group 0..3

  auto compute = [&](int buf) {
#pragma unroll
    for (int p = 0; p < 2; p++) {
      const int lq = g4 * 2 + p;               // logical quad
      const int ph = lq ^ (frow & 7);          // physical quad (swizzle)
      u64x2 aV[2], bV[2];
#pragma unroll
      for (int fm = 0; fm < 2; fm++)
        aV[fm] = *(const u64x2*)&sA[buf][(wm * 32 + fm * 16 + frow) * 128 + ph * 16];
#pragma unroll
      for (int fn = 0; fn < 2; fn++)
        bV[fn] = *(const u64x2*)&sB[(wn * 32 + fn * 16 + frow) * 128 + ph * 16];
#pragma unroll
      for (int fm = 0; fm < 2; fm++)
#pragma unroll
        for (int fn = 0; fn < 2; fn++) {
          acc[fm][fn] = __builtin_amdgcn_mfma_f32_16x16x32_fp8_fp8(
              (long long)aV[fm].x, (long long)bV[fn].x, acc[fm][fn], 0, 0, 0);
          acc[fm][fn] = __builtin_amdgcn_mfma_f32_16x16x32_fp8_fp8(
              (long long)aV[fm].y, (long long)bV[fn].y, acc[fm][fn], 0, 0, 0);
        }
    }
  };

  stageA(0, 0);
  for (int kb = 0; kb < nkb; kb++) {
    asm volatile("" ::: "memory");
    __builtin_amdgcn_s_barrier();                      // BARRIER A: sB + buf free
    asm volatile("" ::: "memory");
    stageB(kb);                                        // issue B(k) FIRST (older)
    if (kb + 1 < nkb) {
      stageA((kb + 1) & 1, kb + 1);                    // then A(k+1) (younger, stays in flight)
      asm volatile("s_waitcnt vmcnt(1)" ::: "memory"); // A(k), B(k) complete; A(k+1) pending
    } else {
      asm volatile("s_waitcnt vmcnt(0)" ::: "memory"); // last tile: drain
    }
    __builtin_amdgcn_s_barrier();                      // BARRIER B: tile resident
    asm volatile("" ::: "memory");
    compute(kb & 1);
  }

  // fused epilogue: C/D layout col = lane&15, row = (lane>>4)*4 + reg  [HW-verified].
  // du bytes from LAST A-tile in LDS: byte (rt,c) at rt*128 + ((c>>4)^(rt&7))*16 + (c&15).
  // Neighbor (c+1) via __shfl_down within 16-lane group; frow==15 reads explicitly.
  const int lastBuf = (nkb - 1) & 1;
  float psum = 0.f;
#pragma unroll
  for (int fm = 0; fm < 2; fm++) {
#pragma unroll
    for (int fn = 0; fn < 2; fn++) {
      const int c = wn * 32 + fn * 16 + frow;    // col within tile
      const int icol = col0 + c;                 // du index i; output position n = i+1
#pragma unroll
      for (int reg = 0; reg < 4; reg++) {
        const int rt = wm * 32 + fm * 16 + g4 * 4 + reg;   // row within tile (0..63)
        float dui = fp8_dec(sA[lastBuf][rt * 128 + (((c >> 4) ^ (rt & 7)) << 4) + (c & 15)]);
        float dnext = __shfl_down(dui, 1, 64);             // dui of (rt, c+1) for frow<15
        if (frow == 15) {
          if (c == 127) {                                  // tile edge: global byte (cb<7)
            dnext = (icol < 1022) ? fp8_dec(du8[(size_t)(row0 + rt) * 1024 + icol + 1]) : 0.f;
          } else {
            const int c1 = c + 1;
            dnext = fp8_dec(sA[lastBuf][rt * 128 + (((c1 >> 4) ^ (rt & 7)) << 4) + (c1 & 15)]);
          }
        }
        if (icol < 1023) {
          float frac = COEF * acc[fm][fn][reg];
          float ut = (icol == 1022) ? dui : 0.5f * (dui + dnext);
          float res = ut - frac;
          psum += res * res;
        }
      }
    }
  }

#pragma unroll
  for (int off = 32; off > 0; off >>= 1) psum += __shfl_down(psum, off, 64);
  if (lane == 0) wsum[w] = psum;

  // pre-reduce this block's 8-row slice of dpart/ppart (wave 0)
  float ds_ = 0.f, ps_ = 0.f;
  if (w == 0) {
    if (t < 8) { ds_ = dpart[bid * 8 + t]; ps_ = ppart[bid * 8 + t]; }
#pragma unroll
    for (int off = 4; off > 0; off >>= 1) {
      ds_ += __shfl_down(ds_, off, 64);
      ps_ += __shfl_down(ps_, off, 64);
    }
  }
  __syncthreads();
  if (t == 0) {
    float s = 0.f;
#pragma unroll
    for (int i = 0; i < 8; i++) s += wsum[i];
    gpart[bid] = s + ps_;
    gpart[1024 + bid] = ds_;
  }
}

// Single-block reduction of 2048 partials -> 3 outputs.
__global__ void finalize(const float* __restrict__ gpart, float* __restrict__ out) {
  const int t = threadIdx.x;    // 256 threads
  float ds = 0.f, ps = 0.f;
  for (int i = t; i < 1024; i += 256) { ps += gpart[i]; ds += gpart[1024 + i]; }

#pragma unroll
  for (int off = 32; off > 0; off >>= 1) {
    ds += __shfl_down(ds, off, 64);
    ps += __shfl_down(ps, off, 64);
  }
  __shared__ float sd[4], sp[4];
  const int lane = t & 63, w = t >> 6;
  if (lane == 0) { sd[w] = ds; sp[w] = ps; }
  __syncthreads();
  if (t == 0) {
    float data = (sd[0] + sd[1] + sd[2] + sd[3]) * INV_COUNT;
    float phys = (sp[0] + sp[1] + sp[2] + sp[3]) * INV_COUNT;
    out[0] = data + 0.1f * phys;
    out[1] = data;
    out[2] = phys;
  }
}

extern "C" void kernel_launch(void* const* d_in, const int* in_sizes, int n_in,
                              void* d_out, int out_size, void* d_ws, size_t ws_size,
                              hipStream_t stream) {
  const float* u_pred = (const float*)d_in[0];
  const float* u_true = (const float*)d_in[1];
  float* out = (float*)d_out;

  char* ws = (char*)d_ws;
  float* dpart = (float*)ws;                                    // 8192 floats (32 KiB)
  float* ppart = (float*)(ws + 32768);                          // 8192 floats (32 KiB)
  float* gpart = (float*)(ws + 65536);                          // 2048 floats (8 KiB)
  unsigned char* Mt8d = (unsigned char*)(ws + 131072);          // 8 tiles * 16 KiB = 128 KiB
  unsigned char* du8 = (unsigned char*)(ws + 131072 + 1048576); // 8192*1024 = 8 MiB

  prep<<<8320, 256, 0, stream>>>(u_pred, u_true, du8, Mt8d, dpart, ppart);
  gemm<<<1024, 512, 0, stream>>>(du8, Mt8d, gpart, dpart, ppart);
  finalize<<<1, 256, 0, stream>>>(gpart, out);
}